// Round 3
// baseline (2657.876 us; speedup 1.0000x reference)
//
#include <hip/hip_runtime.h>

// GRU B=64 S=512 I=512 H=1024 — fp32 in/out, bf16 MFMA compute.
// v4: v2's PROVEN agent-atomic protocol, restructured to halve the MALL
// broadcast and shrink sync fan-in.
//  - 8 batch-groups x 8 batches; 32 blocks/group; each block owns 32 dims.
//    256 blocks x 256 thr (4 waves, 1/CU, 1 wave/SIMD, VGPR budget 512).
//  - weights bf16 in VGPRs: 288 VGPR/lane (3 gates x [8|4] kfrags x 2 nhalves).
//  - M=8: A-frag rows = batch (ln&7), rows 8-15 duplicate -> HW coalesces the
//    duplicate addresses; h broadcast = 4MB/step (was 8MB), fan-in 32 flags
//    over 8 producer blocks (was 64 over 16).
//  - per step: x-MFMAs (prefetched regs) -> poll 32 flags (agent atomics) ->
//    16x u64 agent-atomic h loads -> 48 h-MFMAs -> LDS partial reduce
//    (parity double-buffered, ONE barrier) -> gates -> publish h pairs
//    (agent store) -> vmcnt(0) -> per-wave flag -> NT out store + x prefetch.
// ws: [0,256KB) h ping-pong bf16; +256KB flags[1024] u32 (zeroed per launch).

#define B_ 64
#define S_ 512
#define I_ 512
#define H_ 1024

typedef short short8 __attribute__((ext_vector_type(8)));
typedef float f32x4 __attribute__((ext_vector_type(4)));

__device__ __forceinline__ unsigned short f2bf(float f) {
    unsigned u = __builtin_bit_cast(unsigned, f);
    u += 0x7fffu + ((u >> 16) & 1u);
    return (unsigned short)(u >> 16);
}
__device__ __forceinline__ float sigm(float x) { return 1.f / (1.f + __expf(-x)); }
__device__ __forceinline__ float tanh_(float x) { return 2.f / (1.f + __expf(-2.f * x)) - 1.f; }

__device__ __forceinline__ f32x4 MFMA(short8 a, short8 b, f32x4 c) {
    return __builtin_amdgcn_mfma_f32_16x16x32_bf16(a, b, c, 0, 0, 0);
}

__device__ __forceinline__ short8 cvt8(float4 a, float4 b) {
    short8 r;
    r[0] = (short)f2bf(a.x); r[1] = (short)f2bf(a.y); r[2] = (short)f2bf(a.z); r[3] = (short)f2bf(a.w);
    r[4] = (short)f2bf(b.x); r[5] = (short)f2bf(b.y); r[6] = (short)f2bf(b.z); r[7] = (short)f2bf(b.w);
    return r;
}
__device__ __forceinline__ short8 load8bf(const float* p) {
    return cvt8(*(const float4*)p, *(const float4*)(p + 4));
}

__launch_bounds__(256, 1)
__global__ void gru_persistent(const float* __restrict__ xin,            // [B,S,I] fp32
                               unsigned short* hbase,                    // ws ping-pong bf16
                               unsigned* flags,                          // [8][32][4] u32
                               const float* __restrict__ w_ih,           // [3H,I] fp32
                               const float* __restrict__ w_hh,           // [3H,H] fp32
                               const float* __restrict__ b_ihp,          // [3H] fp32
                               const float* __restrict__ b_hhp,          // [3H] fp32
                               const float* __restrict__ h0,             // [B,H] fp32
                               float* __restrict__ out) {                // fp32 [B,S,H]+[B,H]
    const int tid = threadIdx.x;
    const int w = tid >> 6;        // wave id 0..3: K-slice owner
    const int l = tid & 63;
    const int ln = l & 15;         // A-frag row (batch, &7 dup) / B-frag col (dim)
    const int lq = l >> 4;         // quad -> k sub-offset
    const int grp   = blockIdx.x & 7;     // batch group (8 batches)
    const int slice = blockIdx.x >> 3;    // dim slice (32 dims)
    const int b0 = grp * 8, d0 = slice * 32;

    // ---- startup: weight B-fragments fp32 -> bf16 -> VGPRs (288 VGPR) ----
    // B-frag: lane ln = output dim col (d0 + nh*16 + ln); k = kbase + lq*8 + j
    short8 Whh[3][8][2], Wih[3][4][2];
    #pragma unroll
    for (int g = 0; g < 3; ++g) {
        #pragma unroll
        for (int kf = 0; kf < 8; ++kf) {
            #pragma unroll
            for (int nh = 0; nh < 2; ++nh) {
                int col = d0 + nh * 16 + ln;
                Whh[g][kf][nh] = load8bf(w_hh + (size_t)(g * H_ + col) * H_ + w * 256 + kf * 32 + lq * 8);
            }
        }
        #pragma unroll
        for (int kf = 0; kf < 4; ++kf) {
            #pragma unroll
            for (int nh = 0; nh < 2; ++nh) {
                int col = d0 + nh * 16 + ln;
                Wih[g][kf][nh] = load8bf(w_ih + (size_t)(g * H_ + col) * I_ + w * 128 + kf * 32 + lq * 8);
            }
        }
    }

    // ---- per-thread elementwise assignment: all 256 threads active ----
    const int n_t = tid & 31, m_t = tid >> 5;    // 32 dims x 8 batches
    const int d = d0 + n_t;
    const float b_r  = b_ihp[d]          + b_hhp[d];
    const float b_z  = b_ihp[H_ + d]     + b_hhp[H_ + d];
    const float b_in = b_ihp[2 * H_ + d];
    const float b_hn = b_hhp[2 * H_ + d];
    float hprev = h0[(size_t)(b0 + m_t) * H_ + d];

    // parity-double-buffered reduce scratch: [par][gate][wave][n32][m pad12]
    __shared__ float red[2 * 4 * 4 * 32 * 12];   // 48KB

    const int aoff = (b0 + (ln & 7)) * H_ + w * 256 + lq * 8;          // shorts
    const float* xrow = xin + (size_t)(b0 + (ln & 7)) * S_ * I_ + w * 128 + lq * 8;

    // flags: [grp][slice][wave]. Producer wave w of (grp,slice) -> t+1.
    // Consumer wave w needs dims [256w,256w+256) -> slices [8w,8w+8), all 4
    // waves -> contiguous flag indices [32w, 32w+32): lane l polls one.
    unsigned* const myflag = flags + grp * 128 + slice * 4 + w;
    unsigned* const pollp  = flags + grp * 128 + w * 32 + (l & 31);

    // x prefetch registers (one step ahead): 4 frags x 32B
    float4 xf[8];
    #pragma unroll
    for (int f = 0; f < 4; ++f) {
        xf[2 * f]     = *(const float4*)(xrow + f * 32);
        xf[2 * f + 1] = *(const float4*)(xrow + f * 32 + 4);
    }

    for (int t = 0; t < S_; ++t) {
        // ---- x-gate work first (independent of h, fills the wait window) ----
        short8 xA[4];
        #pragma unroll
        for (int f = 0; f < 4; ++f) xA[f] = cvt8(xf[2 * f], xf[2 * f + 1]);

        f32x4 ar[2] = {{0,0,0,0},{0,0,0,0}}, az[2] = {{0,0,0,0},{0,0,0,0}};
        f32x4 anh[2] = {{0,0,0,0},{0,0,0,0}}, anx[2] = {{0,0,0,0},{0,0,0,0}};
        #pragma unroll
        for (int kf = 0; kf < 4; ++kf) {
            #pragma unroll
            for (int nh = 0; nh < 2; ++nh) {
                ar[nh]  = MFMA(xA[kf], Wih[0][kf][nh], ar[nh]);
                az[nh]  = MFMA(xA[kf], Wih[1][kf][nh], az[nh]);
                anx[nh] = MFMA(xA[kf], Wih[2][kf][nh], anx[nh]);
            }
        }

        // ---- acquire h (v2-proven agent-atomic protocol) ----
        short8 hA[8];
        if (t == 0) {
            #pragma unroll
            for (int kf = 0; kf < 8; ++kf)
                hA[kf] = load8bf(h0 + (size_t)(b0 + (ln & 7)) * H_ + w * 256 + kf * 32 + lq * 8);
        } else {
            int guard = 0;
            for (;;) {
                unsigned fv = __hip_atomic_load(pollp, __ATOMIC_RELAXED, __HIP_MEMORY_SCOPE_AGENT);
                if (__all((int)(fv >= (unsigned)t))) break;
                if ((++guard & 63) == 0) __builtin_amdgcn_s_sleep(1);
                if (guard > (1 << 20)) break;   // safety valve vs hang
            }
            asm volatile("" ::: "memory");      // no hoisting of h loads above the poll
            const unsigned short* hc = hbase + (size_t)(t & 1) * (B_ * H_);
            #pragma unroll
            for (int kf = 0; kf < 8; ++kf) {
                unsigned long long* p = (unsigned long long*)(hc + aoff + kf * 32);
                unsigned long long v0 = __hip_atomic_load(p,     __ATOMIC_RELAXED, __HIP_MEMORY_SCOPE_AGENT);
                unsigned long long v1 = __hip_atomic_load(p + 1, __ATOMIC_RELAXED, __HIP_MEMORY_SCOPE_AGENT);
                unsigned q[4];
                q[0] = (unsigned)v0; q[1] = (unsigned)(v0 >> 32);
                q[2] = (unsigned)v1; q[3] = (unsigned)(v1 >> 32);
                hA[kf] = __builtin_bit_cast(short8, *(ulong2*)q);
            }
        }

        #pragma unroll
        for (int kf = 0; kf < 8; ++kf) {
            #pragma unroll
            for (int nh = 0; nh < 2; ++nh) {
                ar[nh]  = MFMA(hA[kf], Whh[0][kf][nh], ar[nh]);
                az[nh]  = MFMA(hA[kf], Whh[1][kf][nh], az[nh]);
                anh[nh] = MFMA(hA[kf], Whh[2][kf][nh], anh[nh]);
            }
        }

        // ---- partials -> LDS (rows 0-7 valid: lq<2). layout n=nh*16+ln ----
        const int par = t & 1;
        if (lq < 2) {
            #pragma unroll
            for (int nh = 0; nh < 2; ++nh) {
                int nidx = nh * 16 + ln;
                int base0 = (((par * 4 + 0) * 4 + w) * 32 + nidx) * 12 + lq * 4;
                int base1 = (((par * 4 + 1) * 4 + w) * 32 + nidx) * 12 + lq * 4;
                int base2 = (((par * 4 + 2) * 4 + w) * 32 + nidx) * 12 + lq * 4;
                int base3 = (((par * 4 + 3) * 4 + w) * 32 + nidx) * 12 + lq * 4;
                *(f32x4*)&red[base0] = ar[nh];
                *(f32x4*)&red[base1] = az[nh];
                *(f32x4*)&red[base2] = anh[nh];
                *(f32x4*)&red[base3] = anx[nh];
            }
        }
        __syncthreads();   // the ONLY barrier per step

        // ---- reduce over 4 waves; gates; state update ----
        float rp = 0.f, zp = 0.f, nhp = 0.f, nxp = 0.f;
        #pragma unroll
        for (int ww = 0; ww < 4; ++ww) {
            rp  += red[(((par * 4 + 0) * 4 + ww) * 32 + n_t) * 12 + m_t];
            zp  += red[(((par * 4 + 1) * 4 + ww) * 32 + n_t) * 12 + m_t];
            nhp += red[(((par * 4 + 2) * 4 + ww) * 32 + n_t) * 12 + m_t];
            nxp += red[(((par * 4 + 3) * 4 + ww) * 32 + n_t) * 12 + m_t];
        }
        float r = sigm(rp + b_r);
        float z = sigm(zp + b_z);
        float nn = tanh_(nxp + b_in + r * (nhp + b_hn));
        float h = nn + z * (hprev - nn);   // (1-z)*n + z*h
        hprev = h;

        // ---- publish h + per-wave flag (critical path) ----
        if (t < S_ - 1) {
            unsigned short* hnx = hbase + (size_t)((t + 1) & 1) * (B_ * H_);
            unsigned hb16 = f2bf(h);
            unsigned ob = (unsigned)__shfl_xor((int)hb16, 1, 64);
            if ((tid & 1) == 0) {
                unsigned packed = (hb16 & 0xffffu) | (ob << 16);
                __hip_atomic_store((unsigned*)(hnx + (size_t)(b0 + m_t) * H_ + d),
                                   packed, __ATOMIC_RELAXED, __HIP_MEMORY_SCOPE_AGENT);
            }
            // h stores acked at the coherent point before the flag issues
            asm volatile("s_waitcnt vmcnt(0)" ::: "memory");
            if (l == 0)
                __hip_atomic_store(myflag, (unsigned)(t + 1),
                                   __ATOMIC_RELAXED, __HIP_MEMORY_SCOPE_AGENT);
        }

        // ---- off critical path: output store + next-step x prefetch ----
        __builtin_nontemporal_store(h, &out[((size_t)(b0 + m_t) * S_ + t) * H_ + d]);
        if (t == S_ - 1)
            out[(size_t)B_ * S_ * H_ + (size_t)(b0 + m_t) * H_ + d] = h;

        if (t < S_ - 1) {
            const float* xp = xrow + (size_t)(t + 1) * I_;
            #pragma unroll
            for (int f = 0; f < 4; ++f) {
                xf[2 * f]     = *(const float4*)(xp + f * 32);
                xf[2 * f + 1] = *(const float4*)(xp + f * 32 + 4);
            }
        }
    }
}

extern "C" void kernel_launch(void* const* d_in, const int* in_sizes, int n_in,
                              void* d_out, int out_size, void* d_ws, size_t ws_size,
                              hipStream_t stream) {
    const float* xin  = (const float*)d_in[0];   // fp32 [B,S,I]
    const float* h0   = (const float*)d_in[1];   // fp32 [1,B,H]
    const float* w_ih = (const float*)d_in[2];   // fp32 [3H,I]
    const float* w_hh = (const float*)d_in[3];   // fp32 [3H,H]
    const float* b_ih = (const float*)d_in[4];   // fp32 [3H]
    const float* b_hh = (const float*)d_in[5];   // fp32 [3H]
    if (n_in >= 4 && in_sizes[2] == 3 * H_ * H_ && in_sizes[3] == 3 * H_ * I_) {
        const float* tmp = w_ih; w_ih = w_hh; w_hh = tmp;
    }
    float* out = (float*)d_out;
    (void)ws_size;

    unsigned short* hb = (unsigned short*)d_ws;                   // 2 x B*H bf16 = 256KB
    unsigned* flags = (unsigned*)(hb + 2 * (size_t)B_ * H_);      // [8][32][4] u32

    // flags must be zeroed every launch (ws is re-poisoned to 0xAA)
    hipMemsetAsync(flags, 0, 1024 * sizeof(unsigned), stream);

    hipLaunchKernelGGL(gru_persistent, dim3(256), dim3(256), 0, stream,
                       xin, hb, flags, w_ih, w_hh, b_ih, b_hh, h0, out);
}